// Round 10
// baseline (145.254 us; speedup 1.0000x reference)
//
#include <hip/hip_runtime.h>

#ifndef __has_builtin
#define __has_builtin(x) 0
#endif

#if __has_builtin(__builtin_amdgcn_exp2f)
#define FAST_EXP2(x) __builtin_amdgcn_exp2f(x)
#else
#define FAST_EXP2(x) exp2f(x)
#endif
#if __has_builtin(__builtin_amdgcn_rcpf)
#define FAST_RCP(x) __builtin_amdgcn_rcpf(x)
#else
#define FAST_RCP(x) (1.0f / (x))
#endif

#define P_PTS 2048   // points per diagram (problem constant)
#define S_SAMP 128   // samples (problem constant)
#define CHUNK 512    // raw points per block
#define CH 4         // chunks per diagram = P_PTS / CHUNK
#define NTH 256      // threads per block (4 waves)
#define NG 16        // point streams (compacted index mod 16)
#define KS 8         // samples per thread: s = (tid&15) + 16*k
#define REP 4        // DIAGNOSTIC: run the sweep 4x (acc*0.25 at the end) so
                     // perslay outlasts the 42us harness fills and lands in the
                     // top-5 rocprof table.  Sweep instruction mix identical to
                     // R8's real loop; asm barriers stop CSE across sweeps.

// Kernel 1: one block per (diagram n, chunk ch).
// Phase A: stage + pre-fold (A=2^(-c*y), B=2^(c*x), w); ballot-compact into LDS.
// Phase C: slim eval (fma,fma,max,rcp,fma) + depth-2 LDS register prefetch.
__global__ __launch_bounds__(NTH, 4) void perslay_part_kernel(
    const float* __restrict__ diagrams,   // (N, P, 2) f32
    const void*  __restrict__ maskp,      // (N, P) bool(byte) or int32 -- autodetected
    const float* __restrict__ samples,    // (S,) f32
    const float* __restrict__ theta,      // (1,)
    const float* __restrict__ constant,   // (1,)
    const float* __restrict__ power,      // (1,)
    float* __restrict__ ws)               // (N*CH, S) f32 partials
{
    __shared__ float4 pts[CHUNK + 2 * NG];  // +32: depth-2 prefetch addr stays in-bounds
    __shared__ int    woff[9];              // per-(round,wave) counts -> exclusive prefix

    const int n    = blockIdx.x >> 2;     // diagram
    const int ch   = blockIdx.x & 3;      // chunk within diagram
    const int tid  = threadIdx.x;
    const int lane = tid & 63;
    const int wid  = tid >> 6;            // wave id 0..3

    const float th  = theta[0];
    const float cst = constant[0];
    const float pw  = power[0];
    const float c   = th * 1.4426950408889634f;   // theta * log2(e)

    // Mask dtype autodetect: byte-packed bool with valid-prefix -> word0=0x01010101.
    const unsigned int* mw = (const unsigned int*)maskp;
    const bool isByte = (mw[0] > 1u) | (mw[1] > 1u) | (mw[2] > 1u) | (mw[3] > 1u);

    const size_t pbase_g = (size_t)n * P_PTS + (size_t)ch * CHUNK;
    const float2* __restrict__ dg = ((const float2*)diagrams) + pbase_g;

    // ---- Phase A: stage + compact this chunk's 512 points ------------------
    float4 val[2];
    int    rank[2];
    bool   valid[2];

    #pragma unroll
    for (int r = 0; r < 2; ++r) {
        const int p = r * NTH + tid;
        const float2 xy = dg[p];
        bool m;
        if (isByte) m = ((const unsigned char*)maskp)[pbase_g + p] != 0;
        else        m = ((const int*)maskp)[pbase_g + p] != 0;
        const float pers = xy.y - xy.x;
        const float ap   = fabsf(pers);
        float w;
        if (pw == 1.0f)      w = cst * ap;            // benchmark fast path
        else if (pw == 2.0f) w = cst * ap * ap;
        else                 w = cst * powf(ap, pw);
        valid[r] = m && (w != 0.0f);                  // zero-weight points add exactly 0
        const float A = FAST_EXP2(-c * xy.y);         // 2^(-c*y)
        const float B = FAST_EXP2( c * xy.x);         // 2^(+c*x)
        val[r] = make_float4(A, B, w, 0.0f);
        const unsigned long long b = __ballot(valid[r] ? 1 : 0);
        if (lane == 0) woff[r * 4 + wid] = (int)__popcll(b);
        rank[r] = (int)__popcll(b & ((1ull << lane) - 1ull));
    }
    __syncthreads();

    if (tid == 0) {  // exclusive prefix over the 8 (round,wave) chunks
        int run = 0;
        #pragma unroll
        for (int j = 0; j < 8; ++j) { const int t = woff[j]; woff[j] = run; run += t; }
        woff[8] = run;
    }
    __syncthreads();

    #pragma unroll
    for (int r = 0; r < 2; ++r)
        if (valid[r]) pts[woff[r * 4 + wid] + rank[r]] = val[r];
    const int cnt    = woff[8];
    const int padded = (cnt + 2 * NG - 1) & ~(2 * NG - 1);  // multiple of 32 -> jmax even
    if (tid < padded - cnt) pts[cnt + tid] = make_float4(0.0f, 0.0f, 0.0f, 0.0f);
    __syncthreads();

    // ---- Phase C: software-pipelined inner sweep, repeated REP times -------
    const int   g     = tid >> 4;          // stream 0..15
    const int   sbase = tid & 15;          // sample base

    float E[KS], rE[KS], acc[KS];
    #pragma unroll
    for (int k = 0; k < KS; ++k) {
        const float sv = samples[sbase + 16 * k];
        E[k]  = FAST_EXP2( c * sv);        // 2^(+c*s)
        rE[k] = FAST_EXP2(-c * sv);        // 2^(-c*s)
        acc[k] = 0.0f;
    }

    const int jmax = padded >> 4;          // padded / NG, always even
    const float4* __restrict__ pb = pts + g;

#define EVAL(v, SELFN)                                             \
    _Pragma("unroll")                                              \
    for (int k = 0; k < KS; ++k) {                                 \
        const float t1 = fmaf(E[k],  (v).x, 1.0f);                 \
        const float t2 = fmaf(rE[k], (v).y, 1.0f);                 \
        const float u  = SELFN(t1, t2);                            \
        acc[k] = fmaf((v).z, FAST_RCP(u), acc[k]);                 \
    }

#define INNER_LOOP(SELFN)                                          \
    for (int rep = 0; rep < REP; ++rep) {                          \
        if (jmax > 0) {                                            \
            float4 b0 = pb[0];                                     \
            float4 b1 = pb[NG];                                    \
            for (int j = 0; j < jmax; j += 2) {                    \
                const float4 n0 = pb[(j + 2) * NG];  /* prefetch */\
                const float4 n1 = pb[(j + 3) * NG];  /* prefetch */\
                EVAL(b0, SELFN)                                    \
                EVAL(b1, SELFN)                                    \
                b0 = n0; b1 = n1;                                  \
            }                                                      \
        }                                                          \
        /* stop CSE across sweeps: acc becomes opaque, LDS must re-read */ \
        asm volatile("" : : : "memory");                           \
        _Pragma("unroll")                                          \
        for (int k = 0; k < KS; ++k) asm volatile("" : "+v"(acc[k])); \
    }

    if (c >= 0.0f) { INNER_LOOP(fmaxf) } else { INNER_LOOP(fminf) }
#undef INNER_LOOP
#undef EVAL

    // ---- Reduce 16 streams -> ws[(n*CH+ch), s]  (x 1/REP) ------------------
    __syncthreads();                         // all reads of pts done -> safe to alias
    float* part = (float*)pts;               // [NG][S_SAMP] = 8 KB inside pts
    #pragma unroll
    for (int k = 0; k < KS; ++k)
        part[g * S_SAMP + sbase + 16 * k] = acc[k];
    __syncthreads();

    if (tid < S_SAMP) {
        float t = 0.0f;
        #pragma unroll
        for (int gg = 0; gg < NG; ++gg) t += part[gg * S_SAMP + tid];
        ws[(size_t)blockIdx.x * S_SAMP + tid] = t * (1.0f / REP);
    }
}

// Kernel 2: out[n,s] = sum over 4 chunk partials.  Coalesced, trivial.
__global__ __launch_bounds__(256) void perslay_reduce_kernel(
    const float* __restrict__ part,    // (N*CH, S)
    float* __restrict__ out,           // (N, S)
    int total)                         // N*S
{
    const int idx = blockIdx.x * 256 + threadIdx.x;
    if (idx < total) {
        const int n = idx >> 7;
        const int s = idx & (S_SAMP - 1);
        const float* p = part + (size_t)n * CH * S_SAMP + s;
        out[idx] = (p[0] + p[S_SAMP]) + (p[2 * S_SAMP] + p[3 * S_SAMP]);
    }
}

extern "C" void kernel_launch(void* const* d_in, const int* in_sizes, int n_in,
                              void* d_out, int out_size, void* d_ws, size_t ws_size,
                              hipStream_t stream) {
    const float* diagrams = (const float*)d_in[0];
    const void*  mask     = d_in[1];
    const float* samples  = (const float*)d_in[2];
    const float* theta    = (const float*)d_in[3];
    const float* constant = (const float*)d_in[4];
    const float* power    = (const float*)d_in[5];
    float* out = (float*)d_out;
    float* ws  = (float*)d_ws;    // N*CH*S floats = 1 MB, well under ws_size

    const int N = in_sizes[0] / (2 * P_PTS);   // 512
    perslay_part_kernel<<<N * CH, NTH, 0, stream>>>(diagrams, mask, samples,
                                                    theta, constant, power, ws);
    const int total = N * S_SAMP;
    perslay_reduce_kernel<<<(total + 255) / 256, 256, 0, stream>>>(ws, out, total);
}

// Round 11
// 140.682 us; speedup vs baseline: 1.0325x; 1.0325x over previous
//
#include <hip/hip_runtime.h>

#ifndef __has_builtin
#define __has_builtin(x) 0
#endif

#if __has_builtin(__builtin_amdgcn_exp2f)
#define FAST_EXP2(x) __builtin_amdgcn_exp2f(x)
#else
#define FAST_EXP2(x) exp2f(x)
#endif
#if __has_builtin(__builtin_amdgcn_rcpf)
#define FAST_RCP(x) __builtin_amdgcn_rcpf(x)
#else
#define FAST_RCP(x) (1.0f / (x))
#endif

#define P_PTS  2048   // points per diagram (problem constant)
#define S_SAMP 128    // samples (problem constant)
#define ITEM   256    // raw points per work item
#define IPD    (P_PTS / ITEM)   // 8 items per diagram
#define NTH    256    // threads per block (4 waves)
#define NG     16     // point streams (index mod 16)
#define KS     8      // samples per thread: s = (tid&15) + 16*k
#define GRID   1536   // persistent blocks: 6/CU (LDS-limited), all resident

// R11 restructure (from R10 counters: F=18.4us fixed + X=17.4us sweep, tail~1.6x):
//  * persistent blocks + global atomic work queue -> dynamic balance, no tail
//  * item pipeline: issue loads(i+1) -> sweep(i) -> fold/stage(i+1) + park acc
//    -> barrier -> reduce+atomicAdd(i).  ONE barrier per item; global latency
//    and fold hide under the sweep.  Double-buffered pts/part/woff/nxt make
//    every LDS rewrite 2-barriers-separated (race-free).
//  * no ballot-compaction (mask is a valid prefix; invalid points stage as
//    zeros and contribute exactly 0; cnt = last-valid+1 via one ballot/wave —
//    also correct for arbitrary masks since zeros are evaluated harmlessly)
//  * out accumulated by atomicAdd (memset 0 first) -> reduce kernel gone

__global__ void init_ctr_kernel(unsigned int* ctr, unsigned int v) {
    if (threadIdx.x == 0 && blockIdx.x == 0) *ctr = v;
}

__global__ __launch_bounds__(NTH, 4) void perslay_kernel(
    const float* __restrict__ diagrams,   // (N, P, 2) f32
    const void*  __restrict__ maskp,      // (N, P) bool(byte) or int32 -- autodetected
    const float* __restrict__ samples,    // (S,) f32
    const float* __restrict__ theta,      // (1,)
    const float* __restrict__ constant,   // (1,)
    const float* __restrict__ power,      // (1,)
    unsigned int* __restrict__ ctr,       // work-queue counter (in d_ws)
    float* __restrict__ out,              // (N, S) f32, pre-zeroed
    int nitems)                           // N * IPD
{
    __shared__ float4 pts[2][ITEM + 2 * NG];   // staged (A,B,w,0); +32 prefetch pad
    __shared__ float  part[2][NG * S_SAMP];    // per-stream partials
    __shared__ int    woff[2][4];              // per-wave last-valid candidates
    __shared__ unsigned int nxt[2];            // next queue index

    const int tid  = threadIdx.x;
    const int lane = tid & 63;
    const int wid  = tid >> 6;

    const float th  = theta[0];
    const float cst = constant[0];
    const float pw  = power[0];
    const float c   = th * 1.4426950408889634f;   // theta * log2(e)

    // Mask dtype autodetect: byte-packed bool with valid-prefix -> word0=0x01010101.
    const unsigned int* mwords = (const unsigned int*)maskp;
    const bool isByte = (mwords[0] > 1u) | (mwords[1] > 1u) |
                        (mwords[2] > 1u) | (mwords[3] > 1u);

    const int g = tid >> 4, sbase = tid & 15;
    float E[KS], rE[KS], acc[KS];
    #pragma unroll
    for (int k = 0; k < KS; ++k) {
        const float sv = samples[sbase + 16 * k];
        E[k]  = FAST_EXP2( c * sv);
        rE[k] = FAST_EXP2(-c * sv);
        acc[k] = 0.0f;
    }

    // issue global loads for item idx (this thread's point); guarded
    auto LOADI = [&](unsigned int idx, float2& xy, bool& m) {
        xy = make_float2(0.0f, 0.0f); m = false;
        if (idx < (unsigned)nitems) {
            const size_t pb = (size_t)(idx / IPD) * P_PTS +
                              (size_t)(idx % IPD) * ITEM + tid;
            xy = ((const float2*)diagrams)[pb];
            m  = isByte ? (((const unsigned char*)maskp)[pb] != 0)
                        : (((const int*)maskp)[pb] != 0);
        }
    };
    // fold + stage into buffer buf; record per-wave last-valid+1 candidate
    auto STORE = [&](int buf, float2 xy, bool m) {
        float4 v = make_float4(0.0f, 0.0f, 0.0f, 0.0f);
        if (m) {
            const float pers = xy.y - xy.x;
            const float ap   = fabsf(pers);
            float w;
            if (pw == 1.0f)      w = cst * ap;
            else if (pw == 2.0f) w = cst * ap * ap;
            else                 w = cst * powf(ap, pw);
            v = make_float4(FAST_EXP2(-c * xy.y), FAST_EXP2(c * xy.x), w, 0.0f);
        }
        pts[buf][tid] = v;
        const unsigned long long b = __ballot(m ? 1 : 0);
        const int cand = b ? (wid * 64 + 64 - (int)__builtin_clzll(b)) : 0;
        if (lane == 0) woff[buf][wid] = cand;
    };

#define EVAL(v, SELFN)                                             \
    _Pragma("unroll")                                              \
    for (int k = 0; k < KS; ++k) {                                 \
        const float t1 = fmaf(E[k],  (v).x, 1.0f);                 \
        const float t2 = fmaf(rE[k], (v).y, 1.0f);                 \
        const float u  = SELFN(t1, t2);                            \
        acc[k] = fmaf((v).z, FAST_RCP(u), acc[k]);                 \
    }

#define SWEEP(BUF, CNT, SELFN)                                     \
    {                                                              \
        const int jmax = ((CNT + 31) >> 5) << 1;  /* even, <=16 */ \
        const float4* __restrict__ pb = &pts[BUF][g];              \
        if (jmax > 0) {                                            \
            float4 b0 = pb[0], b1 = pb[NG];                        \
            for (int j = 0; j < jmax; j += 2) {                    \
                const float4 n0 = pb[(j + 2) * NG];  /* prefetch */\
                const float4 n1 = pb[(j + 3) * NG];                \
                EVAL(b0, SELFN) EVAL(b1, SELFN)                    \
                b0 = n0; b1 = n1;                                  \
            }                                                      \
        }                                                          \
    }

#define MAINLOOP(SELFN)                                                      \
    {                                                                        \
        unsigned int idx_cur = blockIdx.x;                                   \
        float2 xy; bool m;                                                   \
        LOADI(idx_cur, xy, m);                                               \
        if (tid == 0) nxt[0] = atomicAdd(ctr, 1u);                           \
        STORE(0, xy, m);                                                     \
        __syncthreads();                                                     \
        int cnt_cur = max(max(woff[0][0], woff[0][1]),                       \
                          max(woff[0][2], woff[0][3]));                      \
        unsigned int idx_next = nxt[0];                                      \
        int p = 0;                                                           \
        while (idx_cur < (unsigned)nitems) {                                 \
            LOADI(idx_next, xy, m);              /* in flight over sweep */  \
            if (tid == 0) nxt[p ^ 1] = atomicAdd(ctr, 1u);                   \
            SWEEP(p, cnt_cur, SELFN)                                         \
            STORE(p ^ 1, xy, m);                                             \
            _Pragma("unroll")                                                \
            for (int k = 0; k < KS; ++k) {                                   \
                part[p][g * S_SAMP + sbase + 16 * k] = acc[k];               \
                acc[k] = 0.0f;                                               \
            }                                                                \
            __syncthreads();                                                 \
            if (cnt_cur > 0 && tid < S_SAMP) {                               \
                float t = 0.0f;                                              \
                _Pragma("unroll")                                            \
                for (int gg = 0; gg < NG; ++gg)                              \
                    t += part[p][gg * S_SAMP + tid];                         \
                atomicAdd(&out[(size_t)(idx_cur / IPD) * S_SAMP + tid], t);  \
            }                                                                \
            idx_cur  = idx_next;                                             \
            cnt_cur  = max(max(woff[p ^ 1][0], woff[p ^ 1][1]),              \
                           max(woff[p ^ 1][2], woff[p ^ 1][3]));             \
            idx_next = nxt[p ^ 1];                                           \
            p ^= 1;                                                          \
        }                                                                    \
    }

    if (c >= 0.0f) MAINLOOP(fmaxf) else MAINLOOP(fminf)

#undef MAINLOOP
#undef SWEEP
#undef EVAL
}

extern "C" void kernel_launch(void* const* d_in, const int* in_sizes, int n_in,
                              void* d_out, int out_size, void* d_ws, size_t ws_size,
                              hipStream_t stream) {
    const float* diagrams = (const float*)d_in[0];
    const void*  mask     = d_in[1];
    const float* samples  = (const float*)d_in[2];
    const float* theta    = (const float*)d_in[3];
    const float* constant = (const float*)d_in[4];
    const float* power    = (const float*)d_in[5];
    float* out = (float*)d_out;
    unsigned int* ctr = (unsigned int*)d_ws;

    const int N = in_sizes[0] / (2 * P_PTS);   // 512
    const int nitems = N * IPD;                // 4096

    hipMemsetAsync(d_out, 0, (size_t)out_size * sizeof(float), stream);
    init_ctr_kernel<<<1, 64, 0, stream>>>(ctr, (unsigned int)GRID);
    perslay_kernel<<<GRID, NTH, 0, stream>>>(diagrams, mask, samples, theta,
                                             constant, power, ctr, out, nitems);
}